// Round 8
// baseline (653.931 us; speedup 1.0000x reference)
//
#include <hip/hip_runtime.h>
#include <hip/hip_bf16.h>

// CliffordEPBottleneck: 10x { rho=tanh(h); drive=W_sym@rho+x; h=0.9h+0.1(1-rho^2)drive }
// Core: 10x GEMM (1024 x 4096 x 4096) bf16 MFMA.
//
// R8: barrier-free GEMM. 1-wave (64-thread) blocks, wave tile 64x64
// (mi=4 x ni=4 frags of 16x16x32) -> 16 MFMA per 4 ds_read (2x density of R7).
// B: frag-packed ring-4 LDS via global_load_lds, depth-3 prefetch, counted
// vmcnt(12), ZERO s_barrier (single wave owns the LDS). A: direct bf16x8
// register loads from packed P, double-buffered. split-K=2, grid 2048 =
// 8 blocks/CU. Combine kernel unchanged from R7.

#define NODES 4096
#define KDIM  4096
#define MDIM  1024
#define DLEN  16384
#define HALF_ELEMS 4194304   // MDIM*NODES (one partial plane)

typedef __attribute__((ext_vector_type(8))) __bf16 bf16x8;
typedef __attribute__((ext_vector_type(8))) unsigned short u16x8;
typedef __attribute__((ext_vector_type(4))) float  f32x4;

static __device__ __forceinline__ unsigned short f32_to_bf16(float f) {
    unsigned int u = __float_as_uint(f);
    u += 0x7fffu + ((u >> 16) & 1u);   // round-to-nearest-even
    return (unsigned short)(u >> 16);
}
static __device__ __forceinline__ float bf16_to_f32(unsigned short u) {
    return __uint_as_float(((unsigned int)u) << 16);
}

// ---------------------------------------------------------------------------
// Kernel 1: Wbp = bf16(0.5*(W+W^T)) packed in B-fragment order.
// Element (n, k) at ((k>>5)*256 + (n>>4))*512 + ((n&15)|(((k>>3)&3)<<4))*8 + (k&7)
// -> fragment (k32, n16) is a contiguous 1 KB chunk in MFMA B lane order.
// ---------------------------------------------------------------------------
__global__ __launch_bounds__(256)
void symw_kernel(const float* __restrict__ W, unsigned short* __restrict__ Wbp) {
    __shared__ float Ta[64][64];
    __shared__ float Tb[64][65];
    const int tn = blockIdx.y, tm = blockIdx.x;
    const int c  = threadIdx.x & 63;
    const int r0 = threadIdx.x >> 6;
#pragma unroll
    for (int rr = 0; rr < 16; ++rr) {
        int r = r0 * 16 + rr;
        Ta[r][c] = W[(size_t)(tn * 64 + r) * 4096 + tm * 64 + c];
        Tb[r][c] = W[(size_t)(tm * 64 + r) * 4096 + tn * 64 + c];
    }
    __syncthreads();
#pragma unroll
    for (int rr = 0; rr < 16; ++rr) {
        int r = r0 * 16 + rr;
        float v = 0.5f * (Ta[r][c] + Tb[c][r]);
        int n = tn * 64 + r;
        int k = tm * 64 + c;
        size_t addr = ((size_t)(k >> 5) * 256 + (n >> 4)) * 512
                    + (size_t)((n & 15) | (((k >> 3) & 3) << 4)) * 8 + (k & 7);
        Wbp[addr] = f32_to_bf16(v);
    }
}

// ---------------------------------------------------------------------------
// Kernel 2: h = x ; P0 = packed bf16(tanh(x)) in A-fragment order.
// ---------------------------------------------------------------------------
__global__ __launch_bounds__(256)
void init_kernel(const float* __restrict__ x, float* __restrict__ h,
                 unsigned short* __restrict__ P0) {
    int idx = blockIdx.x * blockDim.x + threadIdx.x;   // over B*NODES = 1M
    int b = idx >> 12;
    int m = idx & 4095;
    f32x4 xv = *(const f32x4*)(x + (size_t)idx * 4);
    *(f32x4*)(h + (size_t)idx * 4) = xv;
    size_t base = ((size_t)(m >> 5) * 64 + (b >> 2)) * 512
                + (size_t)((m >> 3) & 3) * 128 + (m & 7);
#pragma unroll
    for (int c = 0; c < 4; ++c) {
        P0[base + (size_t)((b & 3) * 4 + c) * 8] = f32_to_bf16(tanhf(xv[c]));
    }
}

// ---------------------------------------------------------------------------
// Kernel 3: barrier-free split-K GEMM. grid (64, 16, 2), 64 threads (1 wave).
// Wave = 64x64 output (mi=4 x ni=4). B ring-4 LDS, A register dbuf.
// ---------------------------------------------------------------------------
__global__ __launch_bounds__(64, 2)
void gemm_kernel(const unsigned short* __restrict__ Pcur,
                 const unsigned short* __restrict__ Wbp,
                 unsigned short* __restrict__ Dp) {
    __shared__ unsigned short Bs[4 * 2048];   // 4 ring slots x 4 KB (64x32 frag-major)

    const int lane = threadIdx.x;            // 0..63
    const int bx   = blockIdx.x;             // n-tile (0..63)
    const int by   = blockIdx.y;             // m-tile (0..15)
    const int ks   = blockIdx.z;             // K half
    const int T0   = ks * 64;                // first local k32-tile

    // staging: 4 chunks/thread; chunk j = frag j of the tile (1 KB each)
    size_t soff[4];
#pragma unroll
    for (int j = 0; j < 4; ++j)
        soff[j] = ((size_t)(bx * 4 + j)) * 512 + (size_t)lane * 8;
    size_t aoff[4];
#pragma unroll
    for (int mi = 0; mi < 4; ++mi)
        aoff[mi] = ((size_t)(by * 4 + mi)) * 512 + (size_t)lane * 8;

    f32x4 acc[4][4];
#pragma unroll
    for (int mi = 0; mi < 4; ++mi)
#pragma unroll
        for (int ni = 0; ni < 4; ++ni)
            acc[mi][ni] = (f32x4){0.f, 0.f, 0.f, 0.f};

    bf16x8 aA[4], aB[4];

#define TC(t) ((t) < 63 ? (t) : 63)   // clamp local tile index (uniform tail)

#define STAGE(slot, tl)                                                         \
    do {                                                                        \
        const unsigned short* src =                                             \
            Wbp + (size_t)(T0 + (tl)) * 131072;                                 \
        _Pragma("unroll")                                                       \
        for (int j = 0; j < 4; ++j) {                                           \
            __builtin_amdgcn_global_load_lds(                                   \
                (const __attribute__((address_space(1))) void*)(src + soff[j]), \
                (__attribute__((address_space(3))) void*)                      \
                    (Bs + (slot) * 2048 + j * 512 + lane * 8),                  \
                16, 0, 0);                                                      \
        }                                                                       \
    } while (0)

#define LOADA(s, tl)                                                            \
    do {                                                                        \
        const unsigned short* Pt = Pcur + (size_t)(T0 + (tl)) * 32768;          \
        _Pragma("unroll")                                                       \
        for (int mi = 0; mi < 4; ++mi)                                          \
            s[mi] = *(const bf16x8*)(Pt + aoff[mi]);                            \
    } while (0)

#define COMPUTE(slot, s)                                                        \
    do {                                                                        \
        const unsigned short* Bb = Bs + (slot) * 2048;                          \
        bf16x8 bfr[4];                                                          \
        _Pragma("unroll")                                                       \
        for (int ni = 0; ni < 4; ++ni)                                          \
            bfr[ni] = *(const bf16x8*)(Bb + ni * 512 + lane * 8);               \
        _Pragma("unroll")                                                       \
        for (int mi = 0; mi < 4; ++mi)                                          \
            _Pragma("unroll")                                                   \
            for (int ni = 0; ni < 4; ++ni)                                      \
                acc[mi][ni] = __builtin_amdgcn_mfma_f32_16x16x32_bf16(          \
                    s[mi], bfr[ni], acc[mi][ni], 0, 0, 0);                      \
    } while (0)

    // prologue (issue order matters for vmcnt accounting):
    STAGE(0, 0);        // 4
    LOADA(aA, 0);       // 4
    STAGE(1, 1);        // 4
    STAGE(2, 2);        // 4
    // iter t=0:
    LOADA(aB, 1);       // 4
    STAGE(3, 3);        // 4  -> 24 outstanding
    asm volatile("s_waitcnt vmcnt(16)" ::: "memory");  // stage0 + A0 done
    COMPUTE(0, aA);

    // t = 1..62 (pairs), steady vmcnt(12) = ops issued after tile-t's A-load
    for (int tp = 0; tp < 31; ++tp) {
        const int t = 1 + 2 * tp;            // odd tile -> aB
        LOADA(aA, TC(t + 1));
        STAGE((t + 3) & 3, TC(t + 3));
        asm volatile("s_waitcnt vmcnt(12)" ::: "memory");
        COMPUTE(t & 3, aB);

        const int u = t + 1;                 // even tile -> aA
        LOADA(aB, TC(u + 1));
        STAGE((u + 3) & 3, TC(u + 3));
        asm volatile("s_waitcnt vmcnt(12)" ::: "memory");
        COMPUTE(u & 3, aA);
    }
    // t = 63 (odd -> aB)
    asm volatile("s_waitcnt vmcnt(0)" ::: "memory");
    COMPUTE(3, aB);
#undef STAGE
#undef LOADA
#undef COMPUTE
#undef TC

    // partial write, bf16. C/D: col=lane&15, row=(lane>>4)*4+reg.
    const int lr = lane & 15, lk = lane >> 4;
    unsigned short* D = Dp + (size_t)ks * HALF_ELEMS;
#pragma unroll
    for (int mi = 0; mi < 4; ++mi) {
        int i0 = by * 64 + mi * 16 + lk * 4;
#pragma unroll
        for (int ni = 0; ni < 4; ++ni) {
            int n = bx * 64 + ni * 16 + lr;
#pragma unroll
            for (int r = 0; r < 4; ++r)
                D[(size_t)(i0 + r) * NODES + n] = f32_to_bf16(acc[mi][ni][r]);
        }
    }
}

// ---------------------------------------------------------------------------
// Kernel 4: combine partials + epilogue (unchanged from R7).
// ---------------------------------------------------------------------------
__global__ __launch_bounds__(256)
void combine_kernel(const unsigned short* __restrict__ Dp,
                    const float* __restrict__ x,
                    float* __restrict__ h,
                    unsigned short* __restrict__ Pnxt,
                    float* __restrict__ out) {
    int g  = blockIdx.x * 256 + threadIdx.x;   // 0..131071
    int b  = g >> 9;
    int mg = (g & 511) << 3;                   // m base (multiple of 8)
    size_t hbase = (size_t)b * DLEN + (size_t)mg * 4;

    f32x4 hv[8], xv[8];
#pragma unroll
    for (int e = 0; e < 8; ++e) {
        hv[e] = *(const f32x4*)(h + hbase + e * 4);
        xv[e] = *(const f32x4*)(x + hbase + e * 4);
    }
    u16x8 d0[4], d1[4];
#pragma unroll
    for (int c = 0; c < 4; ++c) {
        d0[c] = *(const u16x8*)(Dp + (size_t)(b * 4 + c) * NODES + mg);
        d1[c] = *(const u16x8*)(Dp + HALF_ELEMS + (size_t)(b * 4 + c) * NODES + mg);
    }
    u16x8 pn[4];
    float o[8];
#pragma unroll
    for (int e = 0; e < 8; ++e) {
#pragma unroll
        for (int c = 0; c < 4; ++c) {
            float p    = bf16_to_f32(d0[c][e]) + bf16_to_f32(d1[c][e]);
            float hvv  = hv[e][c];
            float rho  = tanhf(hvv);
            float drive = p + xv[e][c];
            float hnew = 0.9f * hvv + 0.1f * (1.0f - rho * rho) * drive;
            hv[e][c] = hnew;
            pn[c][e] = f32_to_bf16(tanhf(hnew));
            if (c == 0) o[e] = hnew;
        }
    }
#pragma unroll
    for (int e = 0; e < 8; ++e)
        *(f32x4*)(h + hbase + e * 4) = hv[e];
#pragma unroll
    for (int c = 0; c < 4; ++c) {
        size_t pa = (size_t)(mg >> 5) * 32768 + (size_t)(b >> 2) * 512
                  + (size_t)(((b & 3) * 4 + c) | (((mg >> 3) & 3) << 4)) * 8;
        *(u16x8*)(Pnxt + pa) = pn[c];
    }
    if (out) {
        *(f32x4*)(out + (size_t)b * NODES + mg)     = (f32x4){o[0], o[1], o[2], o[3]};
        *(f32x4*)(out + (size_t)b * NODES + mg + 4) = (f32x4){o[4], o[5], o[6], o[7]};
    }
}

// ---------------------------------------------------------------------------
extern "C" void kernel_launch(void* const* d_in, const int* in_sizes, int n_in,
                              void* d_out, int out_size, void* d_ws, size_t ws_size,
                              hipStream_t stream) {
    const float* x = (const float*)d_in[0];   // (256, 16384) f32
    const float* W = (const float*)d_in[1];   // (4096, 4096) f32
    float* out = (float*)d_out;               // (256, 4096) f32

    char* ws = (char*)d_ws;
    // ws: Wbp 32MB | P0 8MB | P1 8MB | h 16MB | Dp 16MB  (= 80 MB)
    unsigned short* Wbp = (unsigned short*)(ws);
    unsigned short* P0  = (unsigned short*)(ws + ((size_t)32 << 20));
    unsigned short* P1  = (unsigned short*)(ws + ((size_t)40 << 20));
    float*          h   = (float*)(ws + ((size_t)48 << 20));
    unsigned short* Dp  = (unsigned short*)(ws + ((size_t)64 << 20));

    symw_kernel<<<dim3(64, 64), 256, 0, stream>>>(W, Wbp);
    init_kernel<<<dim3(4096), 256, 0, stream>>>(x, h, P0);

    unsigned short* pc = P0;
    unsigned short* pn = P1;
    for (int s = 0; s < 10; ++s) {
        gemm_kernel<<<dim3(64, 16, 2), 64, 0, stream>>>(pc, Wbp, Dp);
        combine_kernel<<<dim3(512), 256, 0, stream>>>(
            Dp, x, h, pn, (s == 9) ? out : nullptr);
        unsigned short* t = pc; pc = pn; pn = t;
    }
}

// Round 9
// 586.746 us; speedup vs baseline: 1.1145x; 1.1145x over previous
//
#include <hip/hip_runtime.h>
#include <hip/hip_bf16.h>

// CliffordEPBottleneck: 10x { rho=tanh(h); drive=W_sym@rho+x; h=0.9h+0.1(1-rho^2)drive }
// Core: 10x GEMM (1024 x 4096 x 4096) bf16 MFMA.
//
// R9: cache-traffic reduction. Operand traffic/step = #mtiles*32MB + #ntiles*8MB.
// R7 (BM64/BN128,splitK2): 768 MB @ ~17 TB/s ~= the measured 45 us -> model:
// L2/L3-BW bound. Now BM=128/BN=128/splitK2: 512 MB (-33%), grid 512 (2 blk/CU,
// 16 waves/CU like R7), wave tile 64x64 (mi4 x ni4, 16 MFMA / 4 ds_read).
// XCD-partitioned block decode: each XCD owns 4 bx-slices (W L2-resident).
// B: frag-packed ring-4 LDS via global_load_lds, counted vmcnt(10), 1 barrier/tile.
// A: direct bf16x8 register loads from packed P.

#define NODES 4096
#define KDIM  4096
#define MDIM  1024
#define DLEN  16384
#define HALF_ELEMS 4194304   // MDIM*NODES (one partial plane)

typedef __attribute__((ext_vector_type(8))) __bf16 bf16x8;
typedef __attribute__((ext_vector_type(8))) unsigned short u16x8;
typedef __attribute__((ext_vector_type(4))) float  f32x4;

static __device__ __forceinline__ unsigned short f32_to_bf16(float f) {
    unsigned int u = __float_as_uint(f);
    u += 0x7fffu + ((u >> 16) & 1u);   // round-to-nearest-even
    return (unsigned short)(u >> 16);
}
static __device__ __forceinline__ float bf16_to_f32(unsigned short u) {
    return __uint_as_float(((unsigned int)u) << 16);
}

// ---------------------------------------------------------------------------
// Kernel 1: Wbp = bf16(0.5*(W+W^T)) packed in B-fragment order.
// Element (n, k) at ((k>>5)*256 + (n>>4))*512 + ((n&15)|(((k>>3)&3)<<4))*8 + (k&7)
// ---------------------------------------------------------------------------
__global__ __launch_bounds__(256)
void symw_kernel(const float* __restrict__ W, unsigned short* __restrict__ Wbp) {
    __shared__ float Ta[64][64];
    __shared__ float Tb[64][65];
    const int tn = blockIdx.y, tm = blockIdx.x;
    const int c  = threadIdx.x & 63;
    const int r0 = threadIdx.x >> 6;
#pragma unroll
    for (int rr = 0; rr < 16; ++rr) {
        int r = r0 * 16 + rr;
        Ta[r][c] = W[(size_t)(tn * 64 + r) * 4096 + tm * 64 + c];
        Tb[r][c] = W[(size_t)(tm * 64 + r) * 4096 + tn * 64 + c];
    }
    __syncthreads();
#pragma unroll
    for (int rr = 0; rr < 16; ++rr) {
        int r = r0 * 16 + rr;
        float v = 0.5f * (Ta[r][c] + Tb[c][r]);
        int n = tn * 64 + r;
        int k = tm * 64 + c;
        size_t addr = ((size_t)(k >> 5) * 256 + (n >> 4)) * 512
                    + (size_t)((n & 15) | (((k >> 3) & 3) << 4)) * 8 + (k & 7);
        Wbp[addr] = f32_to_bf16(v);
    }
}

// ---------------------------------------------------------------------------
// Kernel 2: h = x ; P0 = packed bf16(tanh(x)) in A-fragment order.
// ---------------------------------------------------------------------------
__global__ __launch_bounds__(256)
void init_kernel(const float* __restrict__ x, float* __restrict__ h,
                 unsigned short* __restrict__ P0) {
    int idx = blockIdx.x * blockDim.x + threadIdx.x;   // over B*NODES = 1M
    int b = idx >> 12;
    int m = idx & 4095;
    f32x4 xv = *(const f32x4*)(x + (size_t)idx * 4);
    *(f32x4*)(h + (size_t)idx * 4) = xv;
    size_t base = ((size_t)(m >> 5) * 64 + (b >> 2)) * 512
                + (size_t)((m >> 3) & 3) * 128 + (m & 7);
#pragma unroll
    for (int c = 0; c < 4; ++c) {
        P0[base + (size_t)((b & 3) * 4 + c) * 8] = f32_to_bf16(tanhf(xv[c]));
    }
}

// ---------------------------------------------------------------------------
// Kernel 3: split-K GEMM. grid 512 (flat, XCD-partitioned decode), 256 thr
// (4 waves 2x2). BM=128 BN=128 BK=32; wave = 64x64 (mi4 x ni4).
// ---------------------------------------------------------------------------
__global__ __launch_bounds__(256, 2)
void gemm_kernel(const unsigned short* __restrict__ Pcur,
                 const unsigned short* __restrict__ Wbp,
                 unsigned short* __restrict__ Dp) {
    __shared__ unsigned short Bs[4 * 4096];   // ring-4 x 8 KB (128n x 32k frag-major)

    // XCD-partitioned decode: xcd = id&7 owns bx in {4*xcd .. 4*xcd+3}
    const int id   = blockIdx.x;             // 0..511
    const int bx   = (id & 7) * 4 + ((id >> 3) & 3);   // 0..31
    const int by   = (id >> 5) & 7;                    // 0..7
    const int ks   = id >> 8;                          // 0..1
    const int T0   = ks * 64;

    const int tid  = threadIdx.x;
    const int w    = tid >> 6;
    const int lane = tid & 63;
    const int wm   = w >> 1;                 // 0..1
    const int wn   = w & 1;                  // 0..1

    // staging: 2 chunks/thread (B tile = 8 KB = 512 x 16B)
    size_t soff[2]; int dsto[2];
#pragma unroll
    for (int j = 0; j < 2; ++j) {
        int c = tid + 256 * j;               // 0..511
        soff[j] = ((size_t)(bx * 8 + (c >> 6))) * 512 + (size_t)(c & 63) * 8;
        dsto[j] = c * 8;
    }
    // A frags: rows (by*8 + wm*4 + mi) in 16-row units
    size_t aoff[4];
#pragma unroll
    for (int mi = 0; mi < 4; ++mi)
        aoff[mi] = ((size_t)(by * 8 + wm * 4 + mi)) * 512 + (size_t)lane * 8;
    const int boff = (wn * 4) * 512 + lane * 8;   // + ni*512 (+slot*4096)

    f32x4 acc[4][4];
#pragma unroll
    for (int mi = 0; mi < 4; ++mi)
#pragma unroll
        for (int ni = 0; ni < 4; ++ni)
            acc[mi][ni] = (f32x4){0.f, 0.f, 0.f, 0.f};

    bf16x8 aA[4], aB[4];

#define TC(t) ((t) < 63 ? (t) : 63)   // clamp local tile index (uniform tail)

#define STAGE(slot, tl)                                                         \
    do {                                                                        \
        const unsigned short* src = Wbp + (size_t)(T0 + (tl)) * 131072;         \
        _Pragma("unroll")                                                       \
        for (int j = 0; j < 2; ++j) {                                           \
            __builtin_amdgcn_global_load_lds(                                   \
                (const __attribute__((address_space(1))) void*)(src + soff[j]), \
                (__attribute__((address_space(3))) void*)                      \
                    (Bs + (slot) * 4096 + dsto[j]),                             \
                16, 0, 0);                                                      \
        }                                                                       \
    } while (0)

#define LOADA(s, tl)                                                            \
    do {                                                                        \
        const unsigned short* Pt = Pcur + (size_t)(T0 + (tl)) * 32768;          \
        _Pragma("unroll")                                                       \
        for (int mi = 0; mi < 4; ++mi)                                          \
            s[mi] = *(const bf16x8*)(Pt + aoff[mi]);                            \
    } while (0)

#define COMPUTE(slot, s)                                                        \
    do {                                                                        \
        const unsigned short* Bb = Bs + (slot) * 4096;                          \
        bf16x8 bfr[4];                                                          \
        _Pragma("unroll")                                                       \
        for (int ni = 0; ni < 4; ++ni)                                          \
            bfr[ni] = *(const bf16x8*)(Bb + boff + ni * 512);                   \
        _Pragma("unroll")                                                       \
        for (int mi = 0; mi < 4; ++mi)                                          \
            _Pragma("unroll")                                                   \
            for (int ni = 0; ni < 4; ++ni)                                      \
                acc[mi][ni] = __builtin_amdgcn_mfma_f32_16x16x32_bf16(          \
                    s[mi], bfr[ni], acc[mi][ni], 0, 0, 0);                      \
    } while (0)

    // prologue: stages 0..2, A0 (issue order fixes vmcnt accounting)
    STAGE(0, 0);        // 2
    LOADA(aA, 0);       // 4
    STAGE(1, 1);        // 2
    STAGE(2, 2);        // 2
    // iter 0:
    LOADA(aB, 1);       // 4
    STAGE(3, 3);        // 2   -> 16 outstanding
    asm volatile("s_waitcnt vmcnt(10)" ::: "memory");  // S0 + A0 landed
    __builtin_amdgcn_s_barrier();
    COMPUTE(0, aA);

    // t = 1..62 in pairs; steady vmcnt(10)
    for (int tp = 0; tp < 31; ++tp) {
        const int t = 1 + 2 * tp;            // odd tile -> aB
        LOADA(aA, TC(t + 1));
        STAGE((t + 3) & 3, TC(t + 3));
        asm volatile("s_waitcnt vmcnt(10)" ::: "memory");
        __builtin_amdgcn_s_barrier();
        COMPUTE(t & 3, aB);

        const int u = t + 1;                 // even tile -> aA
        LOADA(aB, TC(u + 1));
        STAGE((u + 3) & 3, TC(u + 3));
        asm volatile("s_waitcnt vmcnt(10)" ::: "memory");
        __builtin_amdgcn_s_barrier();
        COMPUTE(u & 3, aA);
    }
    // t = 63 (odd -> aB)
    asm volatile("s_waitcnt vmcnt(0)" ::: "memory");
    __builtin_amdgcn_s_barrier();
    COMPUTE(3, aB);
#undef STAGE
#undef LOADA
#undef COMPUTE
#undef TC

    // partial write, bf16. C/D: col=lane&15, row=(lane>>4)*4+reg.
    const int lr = lane & 15, lk = lane >> 4;
    unsigned short* D = Dp + (size_t)ks * HALF_ELEMS;
#pragma unroll
    for (int mi = 0; mi < 4; ++mi) {
        int i0 = by * 128 + wm * 64 + mi * 16 + lk * 4;
#pragma unroll
        for (int ni = 0; ni < 4; ++ni) {
            int n = bx * 128 + wn * 64 + ni * 16 + lr;
#pragma unroll
            for (int r = 0; r < 4; ++r)
                D[(size_t)(i0 + r) * NODES + n] = f32_to_bf16(acc[mi][ni][r]);
        }
    }
}

// ---------------------------------------------------------------------------
// Kernel 4: combine partials + epilogue. Last step: write out only.
// ---------------------------------------------------------------------------
__global__ __launch_bounds__(256)
void combine_kernel(const unsigned short* __restrict__ Dp,
                    const float* __restrict__ x,
                    float* __restrict__ h,
                    unsigned short* __restrict__ Pnxt,
                    float* __restrict__ out) {
    int g  = blockIdx.x * 256 + threadIdx.x;   // 0..131071
    int b  = g >> 9;
    int mg = (g & 511) << 3;                   // m base (multiple of 8)
    size_t hbase = (size_t)b * DLEN + (size_t)mg * 4;

    f32x4 hv[8], xv[8];
#pragma unroll
    for (int e = 0; e < 8; ++e) {
        hv[e] = *(const f32x4*)(h + hbase + e * 4);
        xv[e] = *(const f32x4*)(x + hbase + e * 4);
    }
    u16x8 d0[4], d1[4];
#pragma unroll
    for (int c = 0; c < 4; ++c) {
        d0[c] = *(const u16x8*)(Dp + (size_t)(b * 4 + c) * NODES + mg);
        d1[c] = *(const u16x8*)(Dp + HALF_ELEMS + (size_t)(b * 4 + c) * NODES + mg);
    }
    u16x8 pn[4];
    float o[8];
#pragma unroll
    for (int e = 0; e < 8; ++e) {
#pragma unroll
        for (int c = 0; c < 4; ++c) {
            float p    = bf16_to_f32(d0[c][e]) + bf16_to_f32(d1[c][e]);
            float hvv  = hv[e][c];
            float rho  = tanhf(hvv);
            float drive = p + xv[e][c];
            float hnew = 0.9f * hvv + 0.1f * (1.0f - rho * rho) * drive;
            hv[e][c] = hnew;
            pn[c][e] = f32_to_bf16(tanhf(hnew));
            if (c == 0) o[e] = hnew;
        }
    }
    if (Pnxt) {   // not the last step: update h and packed rho
#pragma unroll
        for (int e = 0; e < 8; ++e)
            *(f32x4*)(h + hbase + e * 4) = hv[e];
#pragma unroll
        for (int c = 0; c < 4; ++c) {
            size_t pa = (size_t)(mg >> 5) * 32768 + (size_t)(b >> 2) * 512
                      + (size_t)(((b & 3) * 4 + c) | (((mg >> 3) & 3) << 4)) * 8;
            *(u16x8*)(Pnxt + pa) = pn[c];
        }
    }
    if (out) {
        *(f32x4*)(out + (size_t)b * NODES + mg)     = (f32x4){o[0], o[1], o[2], o[3]};
        *(f32x4*)(out + (size_t)b * NODES + mg + 4) = (f32x4){o[4], o[5], o[6], o[7]};
    }
}

// ---------------------------------------------------------------------------
extern "C" void kernel_launch(void* const* d_in, const int* in_sizes, int n_in,
                              void* d_out, int out_size, void* d_ws, size_t ws_size,
                              hipStream_t stream) {
    const float* x = (const float*)d_in[0];   // (256, 16384) f32
    const float* W = (const float*)d_in[1];   // (4096, 4096) f32
    float* out = (float*)d_out;               // (256, 4096) f32

    char* ws = (char*)d_ws;
    // ws: Wbp 32MB | P0 8MB | P1 8MB | h 16MB | Dp 16MB  (= 80 MB)
    unsigned short* Wbp = (unsigned short*)(ws);
    unsigned short* P0  = (unsigned short*)(ws + ((size_t)32 << 20));
    unsigned short* P1  = (unsigned short*)(ws + ((size_t)40 << 20));
    float*          h   = (float*)(ws + ((size_t)48 << 20));
    unsigned short* Dp  = (unsigned short*)(ws + ((size_t)64 << 20));

    symw_kernel<<<dim3(64, 64), 256, 0, stream>>>(W, Wbp);
    init_kernel<<<dim3(4096), 256, 0, stream>>>(x, h, P0);

    unsigned short* pc = P0;
    unsigned short* pn = P1;
    for (int s = 0; s < 10; ++s) {
        gemm_kernel<<<dim3(512), 256, 0, stream>>>(pc, Wbp, Dp);
        combine_kernel<<<dim3(512), 256, 0, stream>>>(
            Dp, x, h, (s == 9) ? nullptr : pn, (s == 9) ? out : nullptr);
        unsigned short* t = pc; pc = pn; pn = t;
    }
}